// Round 5
// baseline (207.113 us; speedup 1.0000x reference)
//
#include <hip/hip_runtime.h>
#include <hip/hip_bf16.h>

#define Bb 4
#define Ss 512
#define Hh 768
#define Dd 24
#define Mm 96
#define Oo 768

typedef __bf16 bf16x8 __attribute__((ext_vector_type(8)));
typedef float f32x4 __attribute__((ext_vector_type(4)));

// ---------------------------------------------------------------------------
// Kernel A: Zj = H_j @ Wpj, Zi = H_i @ Wpi   (B*S rows, H=768 -> D=24)
// ---------------------------------------------------------------------------
__global__ __launch_bounds__(256) void proj_kernel(
    const float* __restrict__ Hj, const float* __restrict__ Hi,
    const float* __restrict__ Wpj, const float* __restrict__ Wpi,
    float* __restrict__ Zj, float* __restrict__ Zi)
{
    const int row = blockIdx.x;
    const int which = blockIdx.y;
    const float* src = (which ? Hi : Hj) + (size_t)row * Hh;
    const float* W = which ? Wpi : Wpj;
    float* Z = which ? Zi : Zj;
    __shared__ float rowbuf[Hh];
    __shared__ float partial[8][Dd];
    const int tid = threadIdx.x;
    for (int i = tid; i < Hh; i += 256) rowbuf[i] = src[i];
    __syncthreads();
    if (tid < 192) {
        const int d = tid % Dd;
        const int c = tid / Dd;
        const int h0 = c * 96;
        float s = 0.f;
        #pragma unroll 4
        for (int h = h0; h < h0 + 96; ++h) s = fmaf(rowbuf[h], W[h * Dd + d], s);
        partial[c][d] = s;
    }
    __syncthreads();
    if (tid < Dd) {
        float s = 0.f;
        #pragma unroll
        for (int c = 0; c < 8; ++c) s += partial[c][tid];
        Z[(size_t)row * Dd + tid] = s;
    }
}

// ---------------------------------------------------------------------------
// Transpose + fp32->bf16:  dst[c][r] = bf16(src[r][c]),  tiles 32x32
// ---------------------------------------------------------------------------
__global__ __launch_bounds__(256) void transpose_bf16_kernel(
    const float* __restrict__ src, __bf16* __restrict__ dst,
    int R, int C, long sbatch, long dbatch)
{
    const float* s = src + (size_t)blockIdx.z * sbatch;
    __bf16* d = dst + (size_t)blockIdx.z * dbatch;
    __shared__ float t[32][33];
    const int x = threadIdx.x & 31, y = threadIdx.x >> 5;
    const int c0 = blockIdx.x * 32, r0 = blockIdx.y * 32;
    #pragma unroll
    for (int i = 0; i < 4; ++i)
        t[y + 8 * i][x] = s[(size_t)(r0 + y + 8 * i) * C + c0 + x];
    __syncthreads();
    #pragma unroll
    for (int i = 0; i < 4; ++i)
        d[(size_t)(c0 + y + 8 * i) * R + r0 + x] = (__bf16)t[x][y + 8 * i];
}

// ---------------------------------------------------------------------------
// Hj fp32 -> bf16 into segment 1 of concatenated A  ([2048][2304])
// ---------------------------------------------------------------------------
__global__ __launch_bounds__(256) void hjconv_kernel(
    const float* __restrict__ Hjf, __bf16* __restrict__ Ac)
{
    const int idx = blockIdx.x * 256 + threadIdx.x;
    const int row = idx / 96, c8 = idx % 96;
    const float* s = Hjf + (size_t)row * Hh + c8 * 8;
    const float4 u = *(const float4*)s;
    const float4 v = *(const float4*)(s + 4);
    bf16x8 o;
    o[0]=(__bf16)u.x; o[1]=(__bf16)u.y; o[2]=(__bf16)u.z; o[3]=(__bf16)u.w;
    o[4]=(__bf16)v.x; o[5]=(__bf16)v.y; o[6]=(__bf16)v.z; o[7]=(__bf16)v.w;
    *(bf16x8*)&Ac[(size_t)row * 2304 + Hh + c8 * 8] = o;
}

// ---------------------------------------------------------------------------
// wprep: per p, build the pair-GEMM "weight" operand in MFMA-A layout source:
//   Bw[p][m][k], k in [0,64):
//     k<24      : Zj[p,k]*W1h[k][m] + W1i[k][m]           (wcomb)
//     k==24     : tj[p][m] + bs1[m]                       (bias unit column)
//     25..31    : 0
//     32..55    : W1d[k-32][m]
//     56..63    : 0
// grid 256 blocks x 8 p, 256 thr (m = tid < 96 active). Ws1 staged to LDS
// transposed once per block.
// ---------------------------------------------------------------------------
__global__ __launch_bounds__(256) void wprep_kernel(
    const float* __restrict__ Zj, const float* __restrict__ Ws1,
    const float* __restrict__ bs1, __bf16* __restrict__ Bw)
{
    __shared__ float W[96][97];          // W[x][m] = Ws1[x][m]
    const int tid = threadIdx.x;
    for (int i = tid; i < 96 * 96; i += 256)
        W[i / 96][i % 96] = Ws1[i];
    __syncthreads();
    const int m = tid;
    if (m >= 96) return;
    const float bs1m = bs1[m];
    for (int pp = 0; pp < 8; ++pp) {
        const int p = blockIdx.x * 8 + pp;
        const float* zr = Zj + (size_t)p * Dd;
        float tj = bs1m;
        #pragma unroll
        for (int d = 0; d < Dd; ++d) tj = fmaf(zr[d], W[d][m], tj);
        bf16x8 o[8];
        #pragma unroll
        for (int i = 0; i < 8; ++i) {
            #pragma unroll
            for (int j = 0; j < 8; ++j) {
                const int k = i * 8 + j;
                float v;
                if (k < 24)                 v = fmaf(zr[k], W[48 + k][m], W[24 + k][m]);
                else if (k == 24)           v = tj;
                else if (k >= 32 && k < 56) v = W[72 + (k - 32)][m];
                else                        v = 0.f;
                o[i][j] = (__bf16)v;
            }
        }
        __bf16* dst = Bw + (((size_t)p * 96 + m) << 6);
        #pragma unroll
        for (int i = 0; i < 8; ++i) *(bf16x8*)(dst + i * 8) = o[i];
    }
}

// ---------------------------------------------------------------------------
// Kernel B (MFMA): per (b,p) block: logits over all 512 q + softmax -> bf16.
// Operands SWAPPED vs R2-R4: A = Bw[p] (m on C-rows), B = Zi frags (q on
// C-cols) so the relu*ws2 m-reduction is in-lane regs + 2 shfl (was 16).
// Zi loads software-pipelined one t ahead.
// ---------------------------------------------------------------------------
__global__ __launch_bounds__(256) void pair_kernel(
    const float* __restrict__ Zj, const float* __restrict__ Zi,
    const __bf16* __restrict__ Bw, const float* __restrict__ ws2,
    const float* __restrict__ bs2p, const int* __restrict__ mask,
    __bf16* __restrict__ probs)
{
    const int bp = blockIdx.x;
    const int b  = bp >> 9;              // S = 512
    const int tid  = threadIdx.x;
    const int lane = tid & 63;
    const int wid  = tid >> 6;
    const int col  = lane & 15;          // A: m-row index / B: q-col index
    const int g    = lane >> 4;          // k-quad

    __shared__ float logitsl[Ss];
    __shared__ float red[8];

    // A-fragments (weights) from Bw[p]: aw[n][h] <- Bw[p][n*16+col][h*32+g*8]
    bf16x8 aw[6][2];
    #pragma unroll
    for (int n = 0; n < 6; ++n) {
        const __bf16* base = Bw + (((size_t)bp * 96 + n * 16 + col) << 6) + g * 8;
        aw[n][0] = *(const bf16x8*)(base);
        aw[n][1] = *(const bf16x8*)(base + 32);
    }
    // ws2 for C rows m = n*16 + g*4 + r
    float ws2r[6][4];
    #pragma unroll
    for (int n = 0; n < 6; ++n) {
        const float4 w4 = *(const float4*)&ws2[n * 16 + g * 4];
        ws2r[n][0] = w4.x; ws2r[n][1] = w4.y; ws2r[n][2] = w4.z; ws2r[n][3] = w4.w;
    }

    // per-lane Zj slice for abs-diff k's
    float zj8[8];
    if (g < 3) {
        const float* zr = Zj + (size_t)bp * Dd + g * 8;
        const float4 u = *(const float4*)zr;
        const float4 v = *(const float4*)(zr + 4);
        zj8[0]=u.x; zj8[1]=u.y; zj8[2]=u.z; zj8[3]=u.w;
        zj8[4]=v.x; zj8[5]=v.y; zj8[6]=v.z; zj8[7]=v.w;
    } else {
        #pragma unroll
        for (int j = 0; j < 8; ++j) zj8[j] = 0.f;
    }

    const float* zib = Zi + (size_t)b * Ss * Dd;
    const int ko = (g < 3) ? g * 8 : 0;          // g==3 loads dummy (ignored)

    float4 cu, cv;
    {
        const float* zr = zib + (size_t)(wid * 128 + col) * Dd + ko;
        cu = *(const float4*)zr; cv = *(const float4*)(zr + 4);
    }

    for (int t = 0; t < 8; ++t) {
        const float4 u = cu, v = cv;
        if (t + 1 < 8) {
            const float* zr = zib + (size_t)(wid * 128 + (t + 1) * 16 + col) * Dd + ko;
            cu = *(const float4*)zr; cv = *(const float4*)(zr + 4);
        }
        bf16x8 b0, b1;
        if (g < 3) {
            b0[0]=(__bf16)u.x; b0[1]=(__bf16)u.y; b0[2]=(__bf16)u.z; b0[3]=(__bf16)u.w;
            b0[4]=(__bf16)v.x; b0[5]=(__bf16)v.y; b0[6]=(__bf16)v.z; b0[7]=(__bf16)v.w;
            b1[0]=(__bf16)fabsf(zj8[0]-u.x); b1[1]=(__bf16)fabsf(zj8[1]-u.y);
            b1[2]=(__bf16)fabsf(zj8[2]-u.z); b1[3]=(__bf16)fabsf(zj8[3]-u.w);
            b1[4]=(__bf16)fabsf(zj8[4]-v.x); b1[5]=(__bf16)fabsf(zj8[5]-v.y);
            b1[6]=(__bf16)fabsf(zj8[6]-v.z); b1[7]=(__bf16)fabsf(zj8[7]-v.w);
        } else {
            #pragma unroll
            for (int j = 0; j < 8; ++j) { b0[j] = (__bf16)0.f; b1[j] = (__bf16)0.f; }
            b0[0] = (__bf16)1.0f;        // k=24 unit entry -> bias row
        }

        f32x4 acc[6];
        #pragma unroll
        for (int n = 0; n < 6; ++n) acc[n] = (f32x4){0.f, 0.f, 0.f, 0.f};
        #pragma unroll
        for (int n = 0; n < 6; ++n) {
            acc[n] = __builtin_amdgcn_mfma_f32_16x16x32_bf16(aw[n][0], b0, acc[n], 0, 0, 0);
            acc[n] = __builtin_amdgcn_mfma_f32_16x16x32_bf16(aw[n][1], b1, acc[n], 0, 0, 0);
        }

        float lsum = 0.f;
        #pragma unroll
        for (int n = 0; n < 6; ++n)
            #pragma unroll
            for (int r = 0; r < 4; ++r)
                lsum = fmaf(fmaxf(acc[n][r], 0.f), ws2r[n][r], lsum);
        lsum += __shfl_xor(lsum, 16);
        lsum += __shfl_xor(lsum, 32);
        if (lane < 16) logitsl[wid * 128 + t * 16 + lane] = lsum;
    }
    __syncthreads();

    // mask + bias + softmax over 512 q (2 per thread)
    const float bs2v = bs2p[0];
    const int* mrow = mask + (size_t)b * Ss;
    float l0 = logitsl[tid]       + bs2v + (1.0f - (float)mrow[tid])       * (-3.402823466e+38f);
    float l1 = logitsl[tid + 256] + bs2v + (1.0f - (float)mrow[tid + 256]) * (-3.402823466e+38f);
    float vmax = fmaxf(l0, l1);
    #pragma unroll
    for (int off = 32; off > 0; off >>= 1) vmax = fmaxf(vmax, __shfl_xor(vmax, off));
    if (lane == 0) red[wid] = vmax;
    __syncthreads();
    const float mx = fmaxf(fmaxf(red[0], red[1]), fmaxf(red[2], red[3]));
    const float e0 = __expf(l0 - mx);
    const float e1 = __expf(l1 - mx);
    float vs = e0 + e1;
    #pragma unroll
    for (int off = 32; off > 0; off >>= 1) vs += __shfl_xor(vs, off);
    if (lane == 0) red[4 + wid] = vs;
    __syncthreads();
    const float inv = 1.0f / (red[4] + red[5] + red[6] + red[7]);
    __bf16* prow = probs + (size_t)bp * Ss;
    prow[tid] = (__bf16)(e0 * inv);
    prow[tid + 256] = (__bf16)(e1 * inv);
}

// ---------------------------------------------------------------------------
// bf16 MFMA GEMM, 64x64 block tile, BK=64, LDS single-buffer (padded) with
// register prefetch of the next K-slab. 4 waves (2x2), wave tile 32x32.
// MODE 0: ctx = probs@HiT(batch)  -> write A_concat seg0 (ctx) & seg2 (ctx*Hj)
// MODE 1: mhid = relu(Acat@Wv1T + bv1) -> bf16
// MODE 2: out  = alpha*(mhid@Wv2T + bv2) -> fp32
// ---------------------------------------------------------------------------
template<int MODE>
__global__ __launch_bounds__(256) void gemm_kernel(
    const __bf16* __restrict__ A, const __bf16* __restrict__ Bt,
    const float* __restrict__ Hjf, const float* __restrict__ bias,
    const float* __restrict__ alphap,
    __bf16* __restrict__ obf, float* __restrict__ of)
{
    constexpr int K = (MODE == 0) ? 512 : (MODE == 1) ? 2304 : 768;
    constexpr int NIT = K / 64;
    constexpr int LDT = 72;

    __shared__ __bf16 As[64 * LDT];
    __shared__ __bf16 Bs[64 * LDT];

    const int tid = threadIdx.x;
    const int lane = tid & 63;
    const int wid = tid >> 6;
    const int col = lane & 15, g = lane >> 4;
    const int wm = wid >> 1, wn = wid & 1;
    const int r0 = blockIdx.x * 64;
    const int n0 = blockIdx.y * 64;
    const __bf16* Btb = (MODE == 0) ? Bt + (size_t)(r0 >> 9) * (Hh * Ss) : Bt;

    const int srow = tid >> 2;
    const int sc8  = (tid & 3) * 16;
    const __bf16* ag = A   + (size_t)(r0 + srow) * K + sc8;
    const __bf16* bg = Btb + (size_t)(n0 + srow) * K + sc8;
    __bf16* asl = &As[srow * LDT + sc8];
    __bf16* bsl = &Bs[srow * LDT + sc8];

    bf16x8 ra0 = *(const bf16x8*)(ag);
    bf16x8 ra1 = *(const bf16x8*)(ag + 8);
    bf16x8 rb0 = *(const bf16x8*)(bg);
    bf16x8 rb1 = *(const bf16x8*)(bg + 8);

    f32x4 acc[2][2];
    #pragma unroll
    for (int mi = 0; mi < 2; ++mi)
        #pragma unroll
        for (int ni = 0; ni < 2; ++ni) acc[mi][ni] = (f32x4){0.f, 0.f, 0.f, 0.f};

    for (int it = 0; it < NIT; ++it) {
        __syncthreads();
        *(bf16x8*)(asl)     = ra0;
        *(bf16x8*)(asl + 8) = ra1;
        *(bf16x8*)(bsl)     = rb0;
        *(bf16x8*)(bsl + 8) = rb1;
        __syncthreads();
        if (it + 1 < NIT) {
            const int kk = (it + 1) * 64;
            ra0 = *(const bf16x8*)(ag + kk);
            ra1 = *(const bf16x8*)(ag + kk + 8);
            rb0 = *(const bf16x8*)(bg + kk);
            rb1 = *(const bf16x8*)(bg + kk + 8);
        }
        #pragma unroll
        for (int h = 0; h < 2; ++h) {
            bf16x8 a0 = *(const bf16x8*)&As[(wm * 32 + col)      * LDT + h * 32 + g * 8];
            bf16x8 a1 = *(const bf16x8*)&As[(wm * 32 + 16 + col) * LDT + h * 32 + g * 8];
            bf16x8 b0 = *(const bf16x8*)&Bs[(wn * 32 + col)      * LDT + h * 32 + g * 8];
            bf16x8 b1 = *(const bf16x8*)&Bs[(wn * 32 + 16 + col) * LDT + h * 32 + g * 8];
            acc[0][0] = __builtin_amdgcn_mfma_f32_16x16x32_bf16(a0, b0, acc[0][0], 0, 0, 0);
            acc[0][1] = __builtin_amdgcn_mfma_f32_16x16x32_bf16(a0, b1, acc[0][1], 0, 0, 0);
            acc[1][0] = __builtin_amdgcn_mfma_f32_16x16x32_bf16(a1, b0, acc[1][0], 0, 0, 0);
            acc[1][1] = __builtin_amdgcn_mfma_f32_16x16x32_bf16(a1, b1, acc[1][1], 0, 0, 0);
        }
    }

    const float al = (MODE == 2) ? alphap[0] : 0.f;
    #pragma unroll
    for (int mi = 0; mi < 2; ++mi) {
        #pragma unroll
        for (int r = 0; r < 4; ++r) {
            const int row = r0 + wm * 32 + mi * 16 + g * 4 + r;
            #pragma unroll
            for (int ni = 0; ni < 2; ++ni) {
                const int cn = n0 + wn * 32 + ni * 16 + col;
                const float v = acc[mi][ni][r];
                if (MODE == 0) {
                    const float hjv = Hjf[(size_t)row * Hh + cn];
                    obf[(size_t)row * 2304 + cn] = (__bf16)v;
                    obf[(size_t)row * 2304 + 1536 + cn] = (__bf16)(v * hjv);
                } else if (MODE == 1) {
                    obf[(size_t)row * Oo + cn] = (__bf16)fmaxf(v + bias[cn], 0.f);
                } else {
                    of[(size_t)row * Hh + cn] = al * (v + bias[cn]);
                }
            }
        }
    }
}

// ---------------------------------------------------------------------------
extern "C" void kernel_launch(void* const* d_in, const int* in_sizes, int n_in,
                              void* d_out, int out_size, void* d_ws, size_t ws_size,
                              hipStream_t stream)
{
    const float* Hj  = (const float*)d_in[0];
    const float* Hi  = (const float*)d_in[1];
    const float* Wpj = (const float*)d_in[2];
    const float* Wpi = (const float*)d_in[3];
    const float* Ws1 = (const float*)d_in[4];
    const float* bs1 = (const float*)d_in[5];
    const float* ws2 = (const float*)d_in[6];
    const float* bs2 = (const float*)d_in[7];
    const float* Wv1 = (const float*)d_in[8];
    const float* bv1 = (const float*)d_in[9];
    const float* Wv2 = (const float*)d_in[10];
    const float* bv2 = (const float*)d_in[11];
    const float* alpha = (const float*)d_in[12];
    const int* mask  = (const int*)d_in[13];

    float* ws = (float*)d_ws;
    float* Zj = ws;                                      // 49152
    float* Zi = Zj + 49152;                              // 49152
    float* R0f = Zi + 49152;                             // 524288
    float* R1f = R0f + 524288;                           // 786432
    float* Acat_f = R1f + 786432;                        // 2359296
    float* Wv1T_f = Acat_f + 2359296;                    // 884736
    float* Bw_f   = Wv1T_f + 884736;                     // 6291456 floats (25 MB bf16)
    // total ~43.8 MB

    __bf16* probs_bf = (__bf16*)R0f;                     // [2048][512]
    __bf16* Wv2T     = (__bf16*)R0f;                     // [768][768]
    __bf16* HiT      = (__bf16*)R1f;                     // [4][768][512]
    __bf16* mhid_bf  = (__bf16*)R1f;                     // [2048][768]
    __bf16* Acat     = (__bf16*)Acat_f;                  // [2048][2304]
    __bf16* Wv1T     = (__bf16*)Wv1T_f;                  // [768][2304]
    __bf16* Bw       = (__bf16*)Bw_f;                    // [2048][96][64]

    proj_kernel<<<dim3(Bb * Ss, 2), 256, 0, stream>>>(Hj, Hi, Wpj, Wpi, Zj, Zi);
    wprep_kernel<<<dim3(256), 256, 0, stream>>>(Zj, Ws1, bs1, Bw);
    transpose_bf16_kernel<<<dim3(Hh / 32, Ss / 32, Bb), 256, 0, stream>>>(
        Hi, HiT, Ss, Hh, (long)Ss * Hh, (long)Hh * Ss);
    transpose_bf16_kernel<<<dim3(Oo / 32, 3 * Hh / 32, 1), 256, 0, stream>>>(
        Wv1, Wv1T, 3 * Hh, Oo, 0, 0);
    hjconv_kernel<<<dim3(768), 256, 0, stream>>>(Hj, Acat);
    pair_kernel<<<dim3(Bb * Ss), 256, 0, stream>>>(Zj, Zi, Bw, ws2, bs2, mask, probs_bf);
    gemm_kernel<0><<<dim3(2048 / 64, Hh / 64), 256, 0, stream>>>(
        probs_bf, HiT, Hj, nullptr, nullptr, Acat, nullptr);
    transpose_bf16_kernel<<<dim3(Hh / 32, Oo / 32, 1), 256, 0, stream>>>(
        Wv2, Wv2T, Oo, Hh, 0, 0);
    gemm_kernel<1><<<dim3(2048 / 64, Oo / 64), 256, 0, stream>>>(
        Acat, Wv1T, nullptr, bv1, nullptr, mhid_bf, nullptr);
    gemm_kernel<2><<<dim3(2048 / 64, Hh / 64), 256, 0, stream>>>(
        mhid_bf, Wv2T, nullptr, bv2, alpha, nullptr, (float*)d_out);
}